// Round 7
// baseline (1083.212 us; speedup 1.0000x reference)
//
#include <hip/hip_runtime.h>

// MultiClassDiceLoss: labels {1,2,3}, float32 vols with values in {0,1,2,3}.
// dice_l = 2*|A_l & B_l| / (|A_l| + |B_l| + eps); out = 1 - mean(dice_l).
// History:
//  R1 grid-stride float4, 2-deep:  ~415 us (2.6 TB/s eff)
//  R3 block-linear+nt+8-deep:      ~324 us (3.3 TB/s eff)
//  R4 sw pipeline / R5 phase rot / R6 dense-front: all neutral ~325-340 us.
//  => read-path service-rate wall at ~3.3 TB/s (writes do 6.5 TB/s; m13
//     copy's read side was also ~3.15 TB/s). Not latency, not DRAM layout.
//  R7: halve REQUESTED bytes. Values 0/1/2/3 as f32 are distinguished by the
//     upper 16 bits (0x0000/0x3F80/0x4000/0x4040). Load only the high ushort
//     of each float (byte offset 4e+2): 537 MB requested instead of 1073 MB,
//     same cache lines touched. If the wall scales with requested bytes -> 2x.

#define NCNT 9   // c1[1..3], c2[1..3], inter[1..3]
#define EPT 8    // elements per thread per volume per iteration

__global__ void dice_zero_ws(unsigned int* counters) {
    int i = threadIdx.x;
    if (i < NCNT) counters[i] = 0u;
}

__global__ __launch_bounds__(256) void dice_count(const unsigned short* __restrict__ a,
                                                  const unsigned short* __restrict__ b,
                                                  unsigned int* __restrict__ counters,
                                                  int n) {
    unsigned int c[NCNT];
#pragma unroll
    for (int k = 0; k < NCNT; ++k) c[k] = 0u;

    const int T = 256;                    // blockDim.x
    const int CHUNK = T * EPT;            // elements per block-iteration
    const int gstride = gridDim.x * CHUNK;
    const int nfull = (n / gstride) * gstride;

    for (int base = blockIdx.x * CHUNK + (int)threadIdx.x; base < nfull;
         base += gstride) {
        unsigned short av[EPT], bv[EPT];
        // 16 nontemporal u16 loads issued before any consumption:
#pragma unroll
        for (int k = 0; k < EPT; ++k)
            av[k] = __builtin_nontemporal_load(&a[2 * (base + k * T) + 1]);
#pragma unroll
        for (int k = 0; k < EPT; ++k)
            bv[k] = __builtin_nontemporal_load(&b[2 * (base + k * T) + 1]);
        __builtin_amdgcn_sched_barrier(0);
#pragma unroll
        for (int k = 0; k < EPT; ++k) {
            const unsigned v = av[k];
            const unsigned w = bv[k];
            bool a1 = (v == 0x3F80u), a2 = (v == 0x4000u), a3 = (v == 0x4040u);
            bool b1 = (w == 0x3F80u), b2 = (w == 0x4000u), b3 = (w == 0x4040u);
            c[0] += a1; c[1] += a2; c[2] += a3;
            c[3] += b1; c[4] += b2; c[5] += b3;
            c[6] += a1 & b1; c[7] += a2 & b2; c[8] += a3 & b3;
        }
    }

    // remainder (empty for 512^3 with 2048x256 grid; kept for generality)
    for (int e = nfull + blockIdx.x * T + (int)threadIdx.x; e < n;
         e += gridDim.x * T) {
        const unsigned v = a[2 * e + 1];
        const unsigned w = b[2 * e + 1];
        bool a1 = (v == 0x3F80u), a2 = (v == 0x4000u), a3 = (v == 0x4040u);
        bool b1 = (w == 0x3F80u), b2 = (w == 0x4000u), b3 = (w == 0x4040u);
        c[0] += a1; c[1] += a2; c[2] += a3;
        c[3] += b1; c[4] += b2; c[5] += b3;
        c[6] += a1 & b1; c[7] += a2 & b2; c[8] += a3 & b3;
    }

    // wave-level reduction (wave = 64 lanes)
#pragma unroll
    for (int k = 0; k < NCNT; ++k) {
#pragma unroll
        for (int off = 32; off > 0; off >>= 1)
            c[k] += __shfl_down(c[k], off, 64);
    }

    __shared__ unsigned int s[4][NCNT];  // 256 threads -> 4 waves
    const int wave = threadIdx.x >> 6;
    const int lane = threadIdx.x & 63;
    if (lane == 0) {
#pragma unroll
        for (int k = 0; k < NCNT; ++k) s[wave][k] = c[k];
    }
    __syncthreads();
    if (threadIdx.x == 0) {
#pragma unroll
        for (int k = 0; k < NCNT; ++k) {
            unsigned int v = s[0][k] + s[1][k] + s[2][k] + s[3][k];
            atomicAdd(&counters[k], v);
        }
    }
}

__global__ void dice_finalize(const unsigned int* __restrict__ counters,
                              float* __restrict__ out) {
    const double eps = 1.1920928955078125e-07;  // np.float32 eps
    double acc = 0.0;
#pragma unroll
    for (int l = 0; l < 3; ++l) {
        double c1 = (double)counters[l];
        double c2 = (double)counters[3 + l];
        double in = (double)counters[6 + l];
        acc += (2.0 * in) / (c1 + c2 + eps);
    }
    out[0] = (float)(1.0 - acc / 3.0);
}

extern "C" void kernel_launch(void* const* d_in, const int* in_sizes, int n_in,
                              void* d_out, int out_size, void* d_ws, size_t ws_size,
                              hipStream_t stream) {
    const unsigned short* v1 = (const unsigned short*)d_in[0];
    const unsigned short* v2 = (const unsigned short*)d_in[1];
    float* out = (float*)d_out;
    unsigned int* counters = (unsigned int*)d_ws;

    const int n = in_sizes[0];        // 512^3 = 134217728

    dice_zero_ws<<<1, 64, 0, stream>>>(counters);

    const int threads = 256;
    const int blocks = 2048;          // 8 blocks/CU
    dice_count<<<blocks, threads, 0, stream>>>(v1, v2, counters, n);

    dice_finalize<<<1, 1, 0, stream>>>(counters, out);
}

// Round 8
// 969.713 us; speedup vs baseline: 1.1170x; 1.1170x over previous
//
#include <hip/hip_runtime.h>
#include <stdint.h>

// MultiClassDiceLoss: labels {1,2,3}, float32 vols with values in {0,1,2,3}.
// dice_l = 2*|A_l & B_l| / (|A_l| + |B_l| + eps); out = 1 - mean(dice_l).
// History (dice_count kernel only; +~660us fixed harness poison fills):
//  R1 grid-stride float4 2-deep:  ~415 us (2.6 TB/s eff)
//  R3 block-linear+nt+8-deep:     ~324 us (3.3 TB/s eff)
//  R4 sw-pipeline / R5 phase-rot / R6 dense-front: neutral (~325-340 us)
//  R7 u16 high-half loads:        regressed (~355 us)
//  => every VGPR-return read pattern pins at ~3.3 TB/s (m13 copy read side
//     was also ~3.15 TB/s; writes do 6.5 TB/s). R8: last untried datapath —
//     global_load_lds DMA (skips VGPR return). Wave stages 2KiB A + 2KiB B
//     into private LDS, vmcnt(0) drain, ds_read_b128 consume.
//     Also: per-block partial stores instead of zero_ws + atomics.

#define NCNT 9   // c1[1..3], c2[1..3], inter[1..3]
#define NBLK 2048
#define TPB  256

typedef unsigned int v4u __attribute__((ext_vector_type(4)));
typedef __attribute__((address_space(3))) uint8_t lds8_t;
typedef __attribute__((address_space(1))) const uint8_t glb8_t;

#define F1 0x3F800000u
#define F2 0x40000000u
#define F3 0x40400000u

__device__ __forceinline__ void count4u(v4u x, v4u y, unsigned int* c) {
#pragma unroll
    for (int comp = 0; comp < 4; ++comp) {
        const unsigned v = x[comp];
        const unsigned w = y[comp];
        bool a1 = (v == F1), a2 = (v == F2), a3 = (v == F3);
        bool b1 = (w == F1), b2 = (w == F2), b3 = (w == F3);
        c[0] += a1; c[1] += a2; c[2] += a3;
        c[3] += b1; c[4] += b2; c[5] += b3;
        c[6] += a1 & b1; c[7] += a2 & b2; c[8] += a3 & b3;
    }
}

__global__ __launch_bounds__(TPB, 8) void dice_count(const uint8_t* __restrict__ a,
                                                     const uint8_t* __restrict__ b,
                                                     unsigned int* __restrict__ partials,
                                                     long long n_bytes) {
    // [0, 8K): A staging (4 waves x 2 KiB); [8K, 16K): B staging
    __shared__ uint8_t smem[16384];

    unsigned int c[NCNT];
#pragma unroll
    for (int k = 0; k < NCNT; ++k) c[k] = 0u;

    const int w = threadIdx.x >> 6;      // wave id 0..3 (wave-uniform)
    const int l = threadIdx.x & 63;      // lane id

    const long long block_bytes = 8192;  // per volume per block-iteration
    const long long gstride = (long long)gridDim.x * block_bytes;  // 16 MiB
    const int iters = (int)(n_bytes / gstride);

    lds8_t* la = (lds8_t*)&smem[w * 2048];
    lds8_t* lb = (lds8_t*)&smem[8192 + w * 2048];
    const v4u* ra = (const v4u*)&smem[w * 2048 + l * 16];
    const v4u* rb = (const v4u*)&smem[8192 + w * 2048 + l * 16];

    for (int j = 0; j < iters; ++j) {
        const long long base = (long long)j * gstride
                             + (long long)blockIdx.x * block_bytes
                             + (long long)w * 2048 + (long long)l * 16;
        // 4 DMA loads: dest = wave-uniform LDS base (+HW lane*16)
        __builtin_amdgcn_global_load_lds((glb8_t*)(a + base),        la,        16, 0, 0);
        __builtin_amdgcn_global_load_lds((glb8_t*)(a + base + 1024), la + 1024, 16, 0, 0);
        __builtin_amdgcn_global_load_lds((glb8_t*)(b + base),        lb,        16, 0, 0);
        __builtin_amdgcn_global_load_lds((glb8_t*)(b + base + 1024), lb + 1024, 16, 0, 0);
        __builtin_amdgcn_sched_barrier(0);
        __builtin_amdgcn_s_waitcnt(0xF70);   // vmcnt(0), lgkm/exp masked
        __builtin_amdgcn_sched_barrier(0);
        // consume own 16B per chunk (ds_read_b128, wave-private region)
        v4u xa0 = ra[0], xa1 = ra[64];       // +1024 B
        v4u yb0 = rb[0], yb1 = rb[64];
        count4u(xa0, yb0, c);
        count4u(xa1, yb1, c);
    }

    // tail (empty for 512^3 with 2048 blocks; kept for generality)
    {
        const long long done = (long long)iters * gstride;   // bytes
        const unsigned int* au = (const unsigned int*)a;
        const unsigned int* bu = (const unsigned int*)b;
        const long long n_elem = n_bytes >> 2;
        for (long long e = (done >> 2) + blockIdx.x * TPB + threadIdx.x;
             e < n_elem; e += (long long)gridDim.x * TPB) {
            const unsigned v = au[e];
            const unsigned ww = bu[e];
            bool a1 = (v == F1), a2 = (v == F2), a3 = (v == F3);
            bool b1 = (ww == F1), b2 = (ww == F2), b3 = (ww == F3);
            c[0] += a1; c[1] += a2; c[2] += a3;
            c[3] += b1; c[4] += b2; c[5] += b3;
            c[6] += a1 & b1; c[7] += a2 & b2; c[8] += a3 & b3;
        }
    }

    // wave-level reduction (64 lanes)
#pragma unroll
    for (int k = 0; k < NCNT; ++k) {
#pragma unroll
        for (int off = 32; off > 0; off >>= 1)
            c[k] += __shfl_down(c[k], off, 64);
    }

    // cross-wave reduction: reuse staging LDS (all waves past their loops)
    __syncthreads();
    unsigned int* s = (unsigned int*)smem;   // [4][NCNT]
    if (l == 0) {
#pragma unroll
        for (int k = 0; k < NCNT; ++k) s[w * NCNT + k] = c[k];
    }
    __syncthreads();
    if (threadIdx.x == 0) {
#pragma unroll
        for (int k = 0; k < NCNT; ++k) {
            partials[blockIdx.x * NCNT + k] =
                s[0 * NCNT + k] + s[1 * NCNT + k] + s[2 * NCNT + k] + s[3 * NCNT + k];
        }
    }
}

__global__ __launch_bounds__(TPB) void dice_finalize(const unsigned int* __restrict__ partials,
                                                     float* __restrict__ out, int nblk) {
    unsigned int c[NCNT];
#pragma unroll
    for (int k = 0; k < NCNT; ++k) c[k] = 0u;
    for (int bidx = threadIdx.x; bidx < nblk; bidx += TPB) {
#pragma unroll
        for (int k = 0; k < NCNT; ++k) c[k] += partials[bidx * NCNT + k];
    }
#pragma unroll
    for (int k = 0; k < NCNT; ++k) {
#pragma unroll
        for (int off = 32; off > 0; off >>= 1)
            c[k] += __shfl_down(c[k], off, 64);
    }
    __shared__ unsigned int s[4][NCNT];
    const int w = threadIdx.x >> 6;
    const int l = threadIdx.x & 63;
    if (l == 0) {
#pragma unroll
        for (int k = 0; k < NCNT; ++k) s[w][k] = c[k];
    }
    __syncthreads();
    if (threadIdx.x == 0) {
        const double eps = 1.1920928955078125e-07;  // np.float32 eps
        double acc = 0.0;
#pragma unroll
        for (int lab = 0; lab < 3; ++lab) {
            double c1 = (double)(s[0][lab] + s[1][lab] + s[2][lab] + s[3][lab]);
            double c2 = (double)(s[0][3 + lab] + s[1][3 + lab] + s[2][3 + lab] + s[3][3 + lab]);
            double in = (double)(s[0][6 + lab] + s[1][6 + lab] + s[2][6 + lab] + s[3][6 + lab]);
            acc += (2.0 * in) / (c1 + c2 + eps);
        }
        out[0] = (float)(1.0 - acc / 3.0);
    }
}

extern "C" void kernel_launch(void* const* d_in, const int* in_sizes, int n_in,
                              void* d_out, int out_size, void* d_ws, size_t ws_size,
                              hipStream_t stream) {
    const uint8_t* v1 = (const uint8_t*)d_in[0];
    const uint8_t* v2 = (const uint8_t*)d_in[1];
    float* out = (float*)d_out;
    unsigned int* partials = (unsigned int*)d_ws;   // NBLK * NCNT u32

    const long long n_bytes = (long long)in_sizes[0] * 4;  // 512^3 floats

    dice_count<<<NBLK, TPB, 0, stream>>>(v1, v2, partials, n_bytes);
    dice_finalize<<<1, TPB, 0, stream>>>(partials, out, NBLK);
}